// Round 14
// baseline (318.612 us; speedup 1.0000x reference)
//
#include <hip/hip_runtime.h>

#define E_EDGES 1600000
#define BM 128
#define TPB 256
#define NTILES (E_EDGES / BM)   // 12500 exactly
#define GRID 512                // 2 blocks/CU (LDS 2x80KB = 160KB)
#define WOFF 40960              // shorts reserved for weights in d_ws
#define XBF_SHORTS (100000 * 64)

typedef short s16x8 __attribute__((ext_vector_type(8)));
typedef float f32x4 __attribute__((ext_vector_type(4)));
typedef unsigned int u32x2 __attribute__((ext_vector_type(2)));
typedef unsigned int u32x4 __attribute__((ext_vector_type(4)));

__device__ __forceinline__ unsigned short f2bf(float f) {
    unsigned int u = __builtin_bit_cast(unsigned int, f);
    u += 0x7FFFu + ((u >> 16) & 1u);   // RNE
    return (unsigned short)(u >> 16);
}

// v_cvt_pk_bf16_f32: dst.lo = bf16(lo), dst.hi = bf16(hi), RNE (== f2bf pair)
__device__ __forceinline__ unsigned cvtpk(float lo, float hi) {
    unsigned r;
    asm("v_cvt_pk_bf16_f32 %0, %1, %2" : "=v"(r) : "v"(lo), "v"(hi));
    return r;
}

__device__ __forceinline__ s16x8 pack8(float4 a, float4 b) {
    s16x8 r;
    r[0] = (short)f2bf(a.x); r[1] = (short)f2bf(a.y);
    r[2] = (short)f2bf(a.z); r[3] = (short)f2bf(a.w);
    r[4] = (short)f2bf(b.x); r[5] = (short)f2bf(b.y);
    r[6] = (short)f2bf(b.z); r[7] = (short)f2bf(b.w);
    return r;
}

// d_ws layout (shorts): [0,16384) Wnnn^T [128o][128i]; [16384,24576) Wroot^T [128o][64i];
//                       [24576,40960) Wout^T [128o][128i]; [40960, +6.4M) x as bf16
__global__ void prep_w(const float* __restrict__ Wn, const float* __restrict__ Wr,
                       const float* __restrict__ Wo, unsigned short* __restrict__ wt) {
    int t = blockIdx.x * 256 + threadIdx.x;
    if (t < 16384) {
        int o = t >> 7, i = t & 127;
        wt[t] = f2bf(Wn[i * 128 + o]);
    } else if (t < 24576) {
        int q = t - 16384;
        int o = q >> 6, i = q & 63;
        wt[t] = f2bf(Wr[i * 128 + o]);
    } else if (t < 40960) {
        int q = t - 24576;
        int o = q >> 7, i = q & 127;
        wt[t] = f2bf(Wo[i * 128 + o]);
    }
}

__global__ void prep_x(const float* __restrict__ x, unsigned short* __restrict__ xb) {
    int i = blockIdx.x * 256 + threadIdx.x;    // 800000 chunks of 8 floats
    if (i < XBF_SHORTS / 8) {
        const float4* p = (const float4*)(x + (size_t)i * 8);
        *(s16x8*)(xb + (size_t)i * 8) = pack8(p[0], p[1]);
    }
}

// Swapped-operand MFMA: mfma(A = W^T frag [n][k], B = data frag [k][e]).
// C-frag: col(lane&15)=e, row((lane>>4)*4+j)=n -> 4 consecutive n per lane.
// LDS chunk-major [kq][e][8 shorts], e-dim = 128: all accesses linear, bank-even.
// nt=2 n-blocking (each LDS B-frag read feeds 2 MFMAs) + BM=128 (half the
// barriers/idx-loads/loop overhead per edge vs BM=64).
template<bool XBF>
__global__ __launch_bounds__(TPB, 2) void edge_mlp(
    const float* __restrict__ x, const unsigned short* __restrict__ xb,
    const int* __restrict__ eidx, const float* __restrict__ ea,
    const float* __restrict__ bn_g, const float* __restrict__ br_g,
    const float* __restrict__ bo_g,
    const unsigned short* __restrict__ wt, float* __restrict__ out)
{
    __shared__ unsigned short sh_pair[16 * 128 * 8];  // [kq][e][8], 32 KB
    __shared__ unsigned short sh_ea[8 * 128 * 8];     // [kq][e][8], 16 KB
    __shared__ unsigned short sh_hid[16 * 128 * 8];   // [kq][e][8], 32 KB

    const int tid = threadIdx.x;
    const int w   = tid >> 6;        // wave 0..3 -> n in [w*32, w*32+32)
    const int ln  = tid & 63;
    const int lc  = ln & 15;
    const int q   = ln >> 4;         // 0..3

    // gather ownership: thread owns edge-row r (0..127); sub selects src/dst
    // node (full 128B bf16 row); eh selects which half of the ea row (128B fp32)
    const int r   = tid >> 1;        // 0..127
    const int sub = tid & 1;         // 0: src, 1: dst
    const int ihalf = sub ? E_EDGES : 0;
    const int eh  = tid & 1;

    const unsigned short* Wn = wt;
    const unsigned short* Wr = wt + 16384;
    const unsigned short* Wo = wt + 24576;

    // --- pinned weight A-fragments (80 VGPR) ---
    s16x8 wn[2][4], wr[2][2], wo[2][4];
    #pragma unroll
    for (int nt = 0; nt < 2; ++nt) {
        const int n0 = w * 32 + nt * 16 + lc;
        #pragma unroll
        for (int kk = 0; kk < 4; ++kk) wn[nt][kk] = *(const s16x8*)(Wn + n0 * 128 + kk * 32 + q * 8);
        #pragma unroll
        for (int kk = 0; kk < 2; ++kk) wr[nt][kk] = *(const s16x8*)(Wr + n0 * 64 + kk * 32 + q * 8);
        #pragma unroll
        for (int kk = 0; kk < 4; ++kk) wo[nt][kk] = *(const s16x8*)(Wo + n0 * 128 + kk * 32 + q * 8);
    }
    // biases as f32x4 C-init (12 VGPR)
    f32x4 bn4[2], br4[2], bo4[2];
    #pragma unroll
    for (int nt = 0; nt < 2; ++nt) {
        const int nb = w * 32 + nt * 16 + q * 4;
        bn4[nt] = *(const f32x4*)(bn_g + nb);
        br4[nt] = *(const f32x4*)(br_g + nb);
        bo4[nt] = *(const f32x4*)(bo_g + nb);
    }

    // --- pipeline regs: tile t+1 data, tile t+2 index ---
    s16x8 pr[8];                     // XBF: full 128B bf16 node row
    f32x4 ef[8];                     // ea 128B fp32 slice
    int ic, ic_n;

    int tile = blockIdx.x;

    // prologue: tile-0 data, tile-1 index
    ic = eidx[ihalf + tile * BM + r];
    if constexpr (XBF) {
        const s16x8* xp = (const s16x8*)(xb + (size_t)ic * 64);
        #pragma unroll
        for (int k = 0; k < 8; ++k) pr[k] = xp[k];
    } else {
        const f32x4* xp = (const f32x4*)(x + (size_t)ic * 64);
        #pragma unroll
        for (int k = 0; k < 8; ++k) {
            f32x4 a = xp[2 * k], b = xp[2 * k + 1];
            s16x8 t;
            t[0]=(short)f2bf(a[0]); t[1]=(short)f2bf(a[1]); t[2]=(short)f2bf(a[2]); t[3]=(short)f2bf(a[3]);
            t[4]=(short)f2bf(b[0]); t[5]=(short)f2bf(b[1]); t[6]=(short)f2bf(b[2]); t[7]=(short)f2bf(b[3]);
            pr[k] = t;
        }
    }
    {
        const f32x4* ep = (const f32x4*)(ea + (size_t)(tile * BM + r) * 64 + eh * 32);
        #pragma unroll
        for (int k = 0; k < 8; ++k) ef[k] = ep[k];
    }
    {
        int t1 = (tile + GRID < NTILES) ? tile + GRID : tile;
        ic_n = eidx[ihalf + t1 * BM + r];
    }

    for (; tile < NTILES; tile += GRID) {
        const int base = tile * BM;
        const int tn  = (tile + GRID < NTILES) ? tile + GRID : tile;
        const int tnn = (tn + GRID < NTILES) ? tn + GRID : tn;

        // --- A: drain prefetch -> LDS (chunk-major) ---
        #pragma unroll
        for (int i = 0; i < 8; ++i)
            *(s16x8*)((char*)sh_pair + (sub * 8 + i) * 2048 + r * 16) = pr[i];
        #pragma unroll
        for (int i = 0; i < 4; ++i) {
            u32x4 v;
            v[0] = cvtpk(ef[2 * i][0], ef[2 * i][1]);
            v[1] = cvtpk(ef[2 * i][2], ef[2 * i][3]);
            v[2] = cvtpk(ef[2 * i + 1][0], ef[2 * i + 1][1]);
            v[3] = cvtpk(ef[2 * i + 1][2], ef[2 * i + 1][3]);
            *(u32x4*)((char*)sh_ea + (eh * 4 + i) * 2048 + r * 16) = v;
        }

        // --- C: issue tile t+1 loads (latency hidden under D+E) ---
        ic = ic_n;
        if constexpr (XBF) {
            const s16x8* xp = (const s16x8*)(xb + (size_t)ic * 64);
            #pragma unroll
            for (int k = 0; k < 8; ++k) pr[k] = xp[k];
        } else {
            const f32x4* xp = (const f32x4*)(x + (size_t)ic * 64);
            #pragma unroll
            for (int k = 0; k < 8; ++k) {
                f32x4 a = xp[2 * k], b = xp[2 * k + 1];
                s16x8 t;
                t[0]=(short)f2bf(a[0]); t[1]=(short)f2bf(a[1]); t[2]=(short)f2bf(a[2]); t[3]=(short)f2bf(a[3]);
                t[4]=(short)f2bf(b[0]); t[5]=(short)f2bf(b[1]); t[6]=(short)f2bf(b[2]); t[7]=(short)f2bf(b[3]);
                pr[k] = t;
            }
        }
        {
            const f32x4* ep = (const f32x4*)(ea + (size_t)(tn * BM + r) * 64 + eh * 32);
            #pragma unroll
            for (int k = 0; k < 8; ++k) ef[k] = ep[k];
        }
        ic_n = eidx[ihalf + tnn * BM + r];

        __syncthreads();   // barrier1: pair/ea ready; hid E(t-1) reads done

        // --- D: layer 1 -> sh_hid (bias as C-init) ---
        #pragma unroll
        for (int m = 0; m < 8; ++m) {
            const int e = m * 16 + lc;
            s16x8 g0 = *(const s16x8*)((const char*)sh_pair + (0 * 4 + q) * 2048 + e * 16);
            s16x8 g1 = *(const s16x8*)((const char*)sh_pair + (1 * 4 + q) * 2048 + e * 16);
            s16x8 g2 = *(const s16x8*)((const char*)sh_pair + (2 * 4 + q) * 2048 + e * 16);
            s16x8 g3 = *(const s16x8*)((const char*)sh_pair + (3 * 4 + q) * 2048 + e * 16);
            s16x8 e0 = *(const s16x8*)((const char*)sh_ea + (0 * 4 + q) * 2048 + e * 16);
            s16x8 e1 = *(const s16x8*)((const char*)sh_ea + (1 * 4 + q) * 2048 + e * 16);
            f32x4 a1[2], a2[2];
            #pragma unroll
            for (int nt = 0; nt < 2; ++nt) { a1[nt] = bn4[nt]; a2[nt] = br4[nt]; }
            #pragma unroll
            for (int nt = 0; nt < 2; ++nt) {
                a1[nt] = __builtin_amdgcn_mfma_f32_16x16x32_bf16(wn[nt][0], g0, a1[nt], 0, 0, 0);
                a1[nt] = __builtin_amdgcn_mfma_f32_16x16x32_bf16(wn[nt][1], g1, a1[nt], 0, 0, 0);
                a1[nt] = __builtin_amdgcn_mfma_f32_16x16x32_bf16(wn[nt][2], g2, a1[nt], 0, 0, 0);
                a1[nt] = __builtin_amdgcn_mfma_f32_16x16x32_bf16(wn[nt][3], g3, a1[nt], 0, 0, 0);
                a2[nt] = __builtin_amdgcn_mfma_f32_16x16x32_bf16(wr[nt][0], e0, a2[nt], 0, 0, 0);
                a2[nt] = __builtin_amdgcn_mfma_f32_16x16x32_bf16(wr[nt][1], e1, a2[nt], 0, 0, 0);
            }
            #pragma unroll
            for (int nt = 0; nt < 2; ++nt) {
                float h0 = fmaxf(a1[nt][0], 0.f) + fmaxf(a2[nt][0], 0.f);
                float h1 = fmaxf(a1[nt][1], 0.f) + fmaxf(a2[nt][1], 0.f);
                float h2 = fmaxf(a1[nt][2], 0.f) + fmaxf(a2[nt][2], 0.f);
                float h3 = fmaxf(a1[nt][3], 0.f) + fmaxf(a2[nt][3], 0.f);
                u32x2 hv;
                hv[0] = cvtpk(h0, h1);
                hv[1] = cvtpk(h2, h3);
                // n0 = w*32+nt*16+q*4 -> chunk = w*4+nt*2+(q>>1), byte = (q&1)*8
                *(u32x2*)((char*)sh_hid + (w * 4 + nt * 2 + (q >> 1)) * 2048 + e * 16 + (q & 1) * 8) = hv;
            }
        }
        __syncthreads();   // barrier2: hid ready; pair/ea reads done before A(t+1)

        // --- E: layer 2 -> out (bias as C-init, NT stores) ---
        #pragma unroll
        for (int m = 0; m < 8; ++m) {
            const int e = m * 16 + lc;
            s16x8 g0 = *(const s16x8*)((const char*)sh_hid + (0 * 4 + q) * 2048 + e * 16);
            s16x8 g1 = *(const s16x8*)((const char*)sh_hid + (1 * 4 + q) * 2048 + e * 16);
            s16x8 g2 = *(const s16x8*)((const char*)sh_hid + (2 * 4 + q) * 2048 + e * 16);
            s16x8 g3 = *(const s16x8*)((const char*)sh_hid + (3 * 4 + q) * 2048 + e * 16);
            f32x4 a3[2];
            #pragma unroll
            for (int nt = 0; nt < 2; ++nt) a3[nt] = bo4[nt];
            #pragma unroll
            for (int nt = 0; nt < 2; ++nt) {
                a3[nt] = __builtin_amdgcn_mfma_f32_16x16x32_bf16(wo[nt][0], g0, a3[nt], 0, 0, 0);
                a3[nt] = __builtin_amdgcn_mfma_f32_16x16x32_bf16(wo[nt][1], g1, a3[nt], 0, 0, 0);
                a3[nt] = __builtin_amdgcn_mfma_f32_16x16x32_bf16(wo[nt][2], g2, a3[nt], 0, 0, 0);
                a3[nt] = __builtin_amdgcn_mfma_f32_16x16x32_bf16(wo[nt][3], g3, a3[nt], 0, 0, 0);
            }
            #pragma unroll
            for (int nt = 0; nt < 2; ++nt) {
                f32x4 o;
                o[0] = fmaxf(a3[nt][0], 0.f);
                o[1] = fmaxf(a3[nt][1], 0.f);
                o[2] = fmaxf(a3[nt][2], 0.f);
                o[3] = fmaxf(a3[nt][3], 0.f);
                __builtin_nontemporal_store(o, (f32x4*)(out + (size_t)(base + e) * 128 + w * 32 + nt * 16 + q * 4));
            }
        }
    }
}

extern "C" void kernel_launch(void* const* d_in, const int* in_sizes, int n_in,
                              void* d_out, int out_size, void* d_ws, size_t ws_size,
                              hipStream_t stream) {
    const float* x   = (const float*)d_in[0];
    const int*   ei  = (const int*)d_in[1];
    const float* ea  = (const float*)d_in[2];
    const float* Wn  = (const float*)d_in[3];
    const float* bn  = (const float*)d_in[4];
    const float* Wr  = (const float*)d_in[5];
    const float* br  = (const float*)d_in[6];
    const float* Wo  = (const float*)d_in[7];
    const float* bo  = (const float*)d_in[8];
    float* out = (float*)d_out;
    unsigned short* wt = (unsigned short*)d_ws;

    const bool xbf = ws_size >= (size_t)(WOFF + XBF_SHORTS) * sizeof(unsigned short);

    prep_w<<<160, 256, 0, stream>>>(Wn, Wr, Wo, wt);
    if (xbf) {
        prep_x<<<XBF_SHORTS / 8 / 256, 256, 0, stream>>>(x, wt + WOFF);
        edge_mlp<true><<<GRID, TPB, 0, stream>>>(x, wt + WOFF, ei, ea, bn, br, bo, wt, out);
    } else {
        edge_mlp<false><<<GRID, TPB, 0, stream>>>(x, nullptr, ei, ea, bn, br, bo, wt, out);
    }
}

// Round 15
// 280.641 us; speedup vs baseline: 1.1353x; 1.1353x over previous
//
#include <hip/hip_runtime.h>

#define E_EDGES 1600000
#define BM 64
#define TPB 256
#define NTILES (E_EDGES / BM)   // 25000 exactly
#define GRID 768
#define WOFF 40960              // shorts reserved for weights in d_ws
#define XBF_SHORTS (100000 * 64)

typedef short s16x8 __attribute__((ext_vector_type(8)));
typedef float f32x4 __attribute__((ext_vector_type(4)));
typedef unsigned int u32x2 __attribute__((ext_vector_type(2)));
typedef unsigned int u32x4 __attribute__((ext_vector_type(4)));

__device__ __forceinline__ unsigned short f2bf(float f) {
    unsigned int u = __builtin_bit_cast(unsigned int, f);
    u += 0x7FFFu + ((u >> 16) & 1u);   // RNE
    return (unsigned short)(u >> 16);
}

// v_cvt_pk_bf16_f32: dst.lo = bf16(lo), dst.hi = bf16(hi), RNE (== f2bf pair)
__device__ __forceinline__ unsigned cvtpk(float lo, float hi) {
    unsigned r;
    asm("v_cvt_pk_bf16_f32 %0, %1, %2" : "=v"(r) : "v"(lo), "v"(hi));
    return r;
}

__device__ __forceinline__ s16x8 pack8(float4 a, float4 b) {
    s16x8 r;
    r[0] = (short)f2bf(a.x); r[1] = (short)f2bf(a.y);
    r[2] = (short)f2bf(a.z); r[3] = (short)f2bf(a.w);
    r[4] = (short)f2bf(b.x); r[5] = (short)f2bf(b.y);
    r[6] = (short)f2bf(b.z); r[7] = (short)f2bf(b.w);
    return r;
}

// d_ws layout (shorts): [0,16384) Wnnn^T [128o][128i]; [16384,24576) Wroot^T [128o][64i];
//                       [24576,40960) Wout^T [128o][128i]; [40960, +6.4M) x as bf16
__global__ void prep_w(const float* __restrict__ Wn, const float* __restrict__ Wr,
                       const float* __restrict__ Wo, unsigned short* __restrict__ wt) {
    int t = blockIdx.x * 256 + threadIdx.x;
    if (t < 16384) {
        int o = t >> 7, i = t & 127;
        wt[t] = f2bf(Wn[i * 128 + o]);
    } else if (t < 24576) {
        int q = t - 16384;
        int o = q >> 6, i = q & 63;
        wt[t] = f2bf(Wr[i * 128 + o]);
    } else if (t < 40960) {
        int q = t - 24576;
        int o = q >> 7, i = q & 127;
        wt[t] = f2bf(Wo[i * 128 + o]);
    }
}

__global__ void prep_x(const float* __restrict__ x, unsigned short* __restrict__ xb) {
    int i = blockIdx.x * 256 + threadIdx.x;    // 800000 chunks of 8 floats
    if (i < XBF_SHORTS / 8) {
        const float4* p = (const float4*)(x + (size_t)i * 8);
        *(s16x8*)(xb + (size_t)i * 8) = pack8(p[0], p[1]);
    }
}

// Swapped-operand MFMA: mfma(A = W^T frag [n][k], B = data frag [k][e]).
// C-frag: col(lane&15)=e, row((lane>>4)*4+j)=n -> 4 consecutive n per lane.
// LDS chunk-major [kq][e][8 shorts]: all accesses linear, bank-even.
// nt=2 n-blocking: 4 waves, wave w owns n in [w*32,w*32+32) as two 16-n
// subtiles -> every LDS B-frag read feeds TWO MFMAs (halves D/E LDS reads).
// launch_bounds(256,2): reg cap 256; natural demand ~155 -> no forced spill.
template<bool XBF>
__global__ __launch_bounds__(TPB, 2) void edge_mlp(
    const float* __restrict__ x, const unsigned short* __restrict__ xb,
    const int* __restrict__ eidx, const float* __restrict__ ea,
    const float* __restrict__ bn_g, const float* __restrict__ br_g,
    const float* __restrict__ bo_g,
    const unsigned short* __restrict__ wt, float* __restrict__ out)
{
    __shared__ unsigned short sh_pair[16 * 64 * 8];  // [kq][e][8], 16 KB
    __shared__ unsigned short sh_ea[8 * 64 * 8];     // [kq][e][8],  8 KB
    __shared__ unsigned short sh_hid[16 * 64 * 8];   // [kq][e][8], 16 KB

    const int tid = threadIdx.x;
    const int w   = tid >> 6;        // wave 0..3 -> n in [w*32, w*32+32)
    const int ln  = tid & 63;
    const int lc  = ln & 15;
    const int q   = ln >> 4;         // 0..3

    // gather ownership: thread owns edge-row r; pair quarter sub (4 chunks = 64B
    // of one node's half-row); ea 64B slice es
    const int r   = tid >> 2;        // 0..63
    const int sub = tid & 3;         // 0,1: src halves; 2,3: dst halves
    const int ihalf = (sub < 2) ? 0 : E_EDGES;
    const int xo  = (sub & 1) * 32;  // short offset within node row
    const int es  = tid & 3;

    const unsigned short* Wn = wt;
    const unsigned short* Wr = wt + 16384;
    const unsigned short* Wo = wt + 24576;

    // --- pinned weight A-fragments (80 VGPR) ---
    s16x8 wn[2][4], wr[2][2], wo[2][4];
    #pragma unroll
    for (int nt = 0; nt < 2; ++nt) {
        const int n0 = w * 32 + nt * 16 + lc;
        #pragma unroll
        for (int kk = 0; kk < 4; ++kk) wn[nt][kk] = *(const s16x8*)(Wn + n0 * 128 + kk * 32 + q * 8);
        #pragma unroll
        for (int kk = 0; kk < 2; ++kk) wr[nt][kk] = *(const s16x8*)(Wr + n0 * 64 + kk * 32 + q * 8);
        #pragma unroll
        for (int kk = 0; kk < 4; ++kk) wo[nt][kk] = *(const s16x8*)(Wo + n0 * 128 + kk * 32 + q * 8);
    }
    // biases as f32x4 C-init (12 VGPR)
    f32x4 bn4[2], br4[2], bo4[2];
    #pragma unroll
    for (int nt = 0; nt < 2; ++nt) {
        const int nb = w * 32 + nt * 16 + q * 4;
        bn4[nt] = *(const f32x4*)(bn_g + nb);
        br4[nt] = *(const f32x4*)(br_g + nb);
        bo4[nt] = *(const f32x4*)(bo_g + nb);
    }

    // --- pipeline regs: tile t+1 data, tile t+2 index ---
    s16x8 pr[4];                     // XBF: 64B contiguous slice of node row
    float4 pf[8];                    // fallback: 128B fp32 slice
    f32x4 ef[4];                     // ea 64B slice
    int ic, ic_n;

    int tile = blockIdx.x;

    // prologue: tile-0 data, tile-1 index
    ic = eidx[ihalf + tile * BM + r];
    if constexpr (XBF) {
        const s16x8* xp = (const s16x8*)(xb + (size_t)ic * 64 + xo);
        #pragma unroll
        for (int k = 0; k < 4; ++k) pr[k] = xp[k];
    } else {
        const float4* xp = (const float4*)(x + (size_t)ic * 64 + xo);
        #pragma unroll
        for (int k = 0; k < 8; ++k) pf[k] = xp[k];
    }
    {
        const f32x4* ep = (const f32x4*)(ea + (size_t)(tile * BM + r) * 64 + es * 16);
        #pragma unroll
        for (int k = 0; k < 4; ++k) ef[k] = ep[k];
    }
    {
        int t1 = (tile + GRID < NTILES) ? tile + GRID : tile;
        ic_n = eidx[ihalf + t1 * BM + r];
    }

    for (; tile < NTILES; tile += GRID) {
        const int base = tile * BM;
        const int tn  = (tile + GRID < NTILES) ? tile + GRID : tile;
        const int tnn = (tn + GRID < NTILES) ? tn + GRID : tn;

        // --- A: drain prefetch -> LDS (chunk-major) ---
        if constexpr (XBF) {
            #pragma unroll
            for (int i = 0; i < 4; ++i)
                *(s16x8*)((char*)sh_pair + (sub * 4 + i) * 1024 + r * 16) = pr[i];
        } else {
            #pragma unroll
            for (int i = 0; i < 4; ++i)
                *(s16x8*)((char*)sh_pair + (sub * 4 + i) * 1024 + r * 16) = pack8(pf[2 * i], pf[2 * i + 1]);
        }
        #pragma unroll
        for (int i = 0; i < 2; ++i) {
            u32x4 v;
            v[0] = cvtpk(ef[2 * i][0], ef[2 * i][1]);
            v[1] = cvtpk(ef[2 * i][2], ef[2 * i][3]);
            v[2] = cvtpk(ef[2 * i + 1][0], ef[2 * i + 1][1]);
            v[3] = cvtpk(ef[2 * i + 1][2], ef[2 * i + 1][3]);
            *(u32x4*)((char*)sh_ea + (es * 2 + i) * 1024 + r * 16) = v;
        }

        // --- C: issue tile t+1 loads (latency hidden under D+E) ---
        ic = ic_n;
        if constexpr (XBF) {
            const s16x8* xp = (const s16x8*)(xb + (size_t)ic * 64 + xo);
            #pragma unroll
            for (int k = 0; k < 4; ++k) pr[k] = xp[k];
        } else {
            const float4* xp = (const float4*)(x + (size_t)ic * 64 + xo);
            #pragma unroll
            for (int k = 0; k < 8; ++k) pf[k] = xp[k];
        }
        {
            const f32x4* ep = (const f32x4*)(ea + (size_t)(tn * BM + r) * 64 + es * 16);
            #pragma unroll
            for (int k = 0; k < 4; ++k) ef[k] = ep[k];
        }
        ic_n = eidx[ihalf + tnn * BM + r];

        __syncthreads();   // barrier1: pair/ea ready; hid E(t-1) reads done

        // --- D: layer 1 -> sh_hid (bias as C-init) ---
        #pragma unroll
        for (int m = 0; m < 4; ++m) {
            const int e = m * 16 + lc;
            s16x8 g0 = *(const s16x8*)((const char*)sh_pair + (0 * 4 + q) * 1024 + e * 16);
            s16x8 g1 = *(const s16x8*)((const char*)sh_pair + (1 * 4 + q) * 1024 + e * 16);
            s16x8 g2 = *(const s16x8*)((const char*)sh_pair + (2 * 4 + q) * 1024 + e * 16);
            s16x8 g3 = *(const s16x8*)((const char*)sh_pair + (3 * 4 + q) * 1024 + e * 16);
            s16x8 e0 = *(const s16x8*)((const char*)sh_ea + (0 * 4 + q) * 1024 + e * 16);
            s16x8 e1 = *(const s16x8*)((const char*)sh_ea + (1 * 4 + q) * 1024 + e * 16);
            f32x4 a1[2], a2[2];
            #pragma unroll
            for (int nt = 0; nt < 2; ++nt) { a1[nt] = bn4[nt]; a2[nt] = br4[nt]; }
            #pragma unroll
            for (int nt = 0; nt < 2; ++nt) {
                a1[nt] = __builtin_amdgcn_mfma_f32_16x16x32_bf16(wn[nt][0], g0, a1[nt], 0, 0, 0);
                a1[nt] = __builtin_amdgcn_mfma_f32_16x16x32_bf16(wn[nt][1], g1, a1[nt], 0, 0, 0);
                a1[nt] = __builtin_amdgcn_mfma_f32_16x16x32_bf16(wn[nt][2], g2, a1[nt], 0, 0, 0);
                a1[nt] = __builtin_amdgcn_mfma_f32_16x16x32_bf16(wn[nt][3], g3, a1[nt], 0, 0, 0);
                a2[nt] = __builtin_amdgcn_mfma_f32_16x16x32_bf16(wr[nt][0], e0, a2[nt], 0, 0, 0);
                a2[nt] = __builtin_amdgcn_mfma_f32_16x16x32_bf16(wr[nt][1], e1, a2[nt], 0, 0, 0);
            }
            #pragma unroll
            for (int nt = 0; nt < 2; ++nt) {
                float h0 = fmaxf(a1[nt][0], 0.f) + fmaxf(a2[nt][0], 0.f);
                float h1 = fmaxf(a1[nt][1], 0.f) + fmaxf(a2[nt][1], 0.f);
                float h2 = fmaxf(a1[nt][2], 0.f) + fmaxf(a2[nt][2], 0.f);
                float h3 = fmaxf(a1[nt][3], 0.f) + fmaxf(a2[nt][3], 0.f);
                u32x2 hv;
                hv[0] = cvtpk(h0, h1);
                hv[1] = cvtpk(h2, h3);
                // n0 = w*32+nt*16+q*4 -> chunk = w*4+nt*2+(q>>1), byte = (q&1)*8
                *(u32x2*)((char*)sh_hid + (w * 4 + nt * 2 + (q >> 1)) * 1024 + e * 16 + (q & 1) * 8) = hv;
            }
        }
        __syncthreads();   // barrier2: hid ready; pair/ea reads done before A(t+1)

        // --- E: layer 2 -> out (bias as C-init) ---
        #pragma unroll
        for (int m = 0; m < 4; ++m) {
            const int e = m * 16 + lc;
            s16x8 g0 = *(const s16x8*)((const char*)sh_hid + (0 * 4 + q) * 1024 + e * 16);
            s16x8 g1 = *(const s16x8*)((const char*)sh_hid + (1 * 4 + q) * 1024 + e * 16);
            s16x8 g2 = *(const s16x8*)((const char*)sh_hid + (2 * 4 + q) * 1024 + e * 16);
            s16x8 g3 = *(const s16x8*)((const char*)sh_hid + (3 * 4 + q) * 1024 + e * 16);
            f32x4 a3[2];
            #pragma unroll
            for (int nt = 0; nt < 2; ++nt) a3[nt] = bo4[nt];
            #pragma unroll
            for (int nt = 0; nt < 2; ++nt) {
                a3[nt] = __builtin_amdgcn_mfma_f32_16x16x32_bf16(wo[nt][0], g0, a3[nt], 0, 0, 0);
                a3[nt] = __builtin_amdgcn_mfma_f32_16x16x32_bf16(wo[nt][1], g1, a3[nt], 0, 0, 0);
                a3[nt] = __builtin_amdgcn_mfma_f32_16x16x32_bf16(wo[nt][2], g2, a3[nt], 0, 0, 0);
                a3[nt] = __builtin_amdgcn_mfma_f32_16x16x32_bf16(wo[nt][3], g3, a3[nt], 0, 0, 0);
            }
            #pragma unroll
            for (int nt = 0; nt < 2; ++nt) {
                f32x4 o;
                o[0] = fmaxf(a3[nt][0], 0.f);
                o[1] = fmaxf(a3[nt][1], 0.f);
                o[2] = fmaxf(a3[nt][2], 0.f);
                o[3] = fmaxf(a3[nt][3], 0.f);
                *(f32x4*)(out + (size_t)(base + e) * 128 + w * 32 + nt * 16 + q * 4) = o;
            }
        }
    }
}

extern "C" void kernel_launch(void* const* d_in, const int* in_sizes, int n_in,
                              void* d_out, int out_size, void* d_ws, size_t ws_size,
                              hipStream_t stream) {
    const float* x   = (const float*)d_in[0];
    const int*   ei  = (const int*)d_in[1];
    const float* ea  = (const float*)d_in[2];
    const float* Wn  = (const float*)d_in[3];
    const float* bn  = (const float*)d_in[4];
    const float* Wr  = (const float*)d_in[5];
    const float* br  = (const float*)d_in[6];
    const float* Wo  = (const float*)d_in[7];
    const float* bo  = (const float*)d_in[8];
    float* out = (float*)d_out;
    unsigned short* wt = (unsigned short*)d_ws;

    const bool xbf = ws_size >= (size_t)(WOFF + XBF_SHORTS) * sizeof(unsigned short);

    prep_w<<<160, 256, 0, stream>>>(Wn, Wr, Wo, wt);
    if (xbf) {
        prep_x<<<XBF_SHORTS / 8 / 256, 256, 0, stream>>>(x, wt + WOFF);
        edge_mlp<true><<<GRID, TPB, 0, stream>>>(x, wt + WOFF, ei, ea, bn, br, bo, wt, out);
    } else {
        edge_mlp<false><<<GRID, TPB, 0, stream>>>(x, nullptr, ei, ea, bn, br, bo, wt, out);
    }
}